// Round 1
// baseline (248.713 us; speedup 1.0000x reference)
//
#include <hip/hip_runtime.h>

typedef unsigned short ushort_t;
typedef unsigned int uint32;
typedef __bf16 bf16x8 __attribute__((ext_vector_type(8)));
typedef float f32x4 __attribute__((ext_vector_type(4)));
typedef float f4 __attribute__((ext_vector_type(4)));
typedef unsigned short us4 __attribute__((ext_vector_type(4)));

// ---- constants for this problem shape ----
// B=16, QL=1024, KL=1024, QS=512, KS=512, KW=3, PAD=1
// M1 = B*QL = 16384, N1 = KS*KW = 1536, K1 = QS = 512
// stage2: per-b GEMM  M=1024(i) x N=1024(j), K=512, 3 shifted passes (t)

__device__ __forceinline__ ushort_t f2bf(float f) {
    uint32 u = __builtin_bit_cast(uint32, f);
    u = (u + 0x7fffu + ((u >> 16) & 1u)) >> 16;  // RNE
    return (ushort_t)u;
}

// ---------------- prep: q -> bf16, and bias[m] = dot(q[m], Wb) + bb ----------------
__global__ __launch_bounds__(256) void prep_q(const float* __restrict__ q,
                                              const float* __restrict__ Wb,
                                              const float* __restrict__ bb,
                                              ushort_t* __restrict__ qb,
                                              float* __restrict__ biasw) {
    const int tid = threadIdx.x;
    const int lane = tid & 63, wid = tid >> 6;
    const int m = blockIdx.x * 4 + wid;           // 16384 rows, one wave per row
    const float* qrow = q + (size_t)m * 512;

    f4 v0 = *(const f4*)(qrow + lane * 4);
    f4 v1 = *(const f4*)(qrow + 256 + lane * 4);
    f4 w0 = *(const f4*)(Wb + lane * 4);
    f4 w1 = *(const f4*)(Wb + 256 + lane * 4);

    float dot = v0[0]*w0[0] + v0[1]*w0[1] + v0[2]*w0[2] + v0[3]*w0[3]
              + v1[0]*w1[0] + v1[1]*w1[1] + v1[2]*w1[2] + v1[3]*w1[3];

    us4 o0, o1;
    o0[0]=f2bf(v0[0]); o0[1]=f2bf(v0[1]); o0[2]=f2bf(v0[2]); o0[3]=f2bf(v0[3]);
    o1[0]=f2bf(v1[0]); o1[1]=f2bf(v1[1]); o1[2]=f2bf(v1[2]); o1[3]=f2bf(v1[3]);
    *(us4*)(qb + (size_t)m * 512 + lane * 4) = o0;
    *(us4*)(qb + (size_t)m * 512 + 256 + lane * 4) = o1;

    #pragma unroll
    for (int off = 32; off >= 1; off >>= 1) dot += __shfl_xor(dot, off);
    if (lane == 0) biasw[m] = dot + bb[0];
}

// ------- prep: k -> bf16 zero-padded [b][1026][512]; Wk row-permuted -> bf16; bk perm -------
__global__ __launch_bounds__(256) void prep_k(const float* __restrict__ k,
                                              const float* __restrict__ Wk,
                                              const float* __restrict__ bk,
                                              ushort_t* __restrict__ kbp,
                                              ushort_t* __restrict__ wkb,
                                              float* __restrict__ bkp) {
    const int gid = blockIdx.x * 256 + threadIdx.x;
    if (gid < 1536) bkp[gid] = bk[(gid & 511) * 3 + (gid >> 9)];

    const int KG = (16 * 1024 * 512) / 4;   // 2,097,152 float4 groups of k
    const int PG = (16 * 2 * 512) / 4;      // 4,096 pad groups

    if (gid < KG) {
        const int e = gid * 4;
        const int b = e >> 19;
        const int rem = e & ((1 << 19) - 1);
        const int row = rem >> 9, c = rem & 511;
        f4 v = *(const f4*)(k + e);
        us4 o; o[0]=f2bf(v[0]); o[1]=f2bf(v[1]); o[2]=f2bf(v[2]); o[3]=f2bf(v[3]);
        *(us4*)(kbp + ((size_t)b * 1026 + row + 1) * 512 + c) = o;
    } else if (gid < KG + PG) {
        const int p = gid - KG;
        const int b = p >> 8, off = p & 255;
        const int row = (off < 128) ? 0 : 1025;
        const int c = (off & 127) * 4;
        us4 z; z[0]=0; z[1]=0; z[2]=0; z[3]=0;
        *(us4*)(kbp + ((size_t)b * 1026 + row) * 512 + c) = z;
    } else {
        const int w = gid - KG - PG;          // 196,608 groups of Wk
        const int n = w >> 7;                 // 0..1535 (permuted row index)
        const int c = (w & 127) * 4;
        const int o = (n & 511) * 3 + (n >> 9);   // original Wk row
        f4 v = *(const f4*)(Wk + (size_t)o * 512 + c);
        us4 ov; ov[0]=f2bf(v[0]); ov[1]=f2bf(v[1]); ov[2]=f2bf(v[2]); ov[3]=f2bf(v[3]);
        *(us4*)(wkb + (size_t)n * 512 + c) = ov;
    }
}

// ---------------- shared GEMM machinery: 128x128 tile, BK=32, 4 waves 2x2 ----------------
__device__ __forceinline__ void stage_tile(const char* gsrc, int ld_bytes, char* lds, int tid) {
    // 128 rows x 64 bytes per K-step; 2 insts x 256 threads x 16B
    #pragma unroll
    for (int inst = 0; inst < 2; ++inst) {
        const int fb = inst * 4096 + tid * 16;  // byte offset in linear [128][64B] tile
        const int row = fb >> 6;
        const int cb = fb & 63;
        const char* g = gsrc + (size_t)row * ld_bytes + cb;
        char* l = lds + inst * 4096 + ((tid >> 6) << 10);   // wave-uniform dest
        __builtin_amdgcn_global_load_lds((const __attribute__((address_space(1))) void*)g,
                                         (__attribute__((address_space(3))) void*)l,
                                         16, 0, 0);
    }
}

// stage 1: coef[m][n] = sum_k qb[m][k]*wkb[n][k] + bkp[n], bf16 out (n already permuted)
__global__ __launch_bounds__(256) void gemm1(const ushort_t* __restrict__ qb,
                                             const ushort_t* __restrict__ wkb,
                                             const float* __restrict__ bkp,
                                             ushort_t* __restrict__ coef) {
    __shared__ alignas(16) char lA[8192];
    __shared__ alignas(16) char lB[8192];
    const int tid = threadIdx.x;
    const int lane = tid & 63, wid = tid >> 6;
    const int wr = wid >> 1, wc = wid & 1;
    const int mbase = blockIdx.x * 128;
    const int nbase = blockIdx.y * 128;

    f32x4 acc[4][4];
    #pragma unroll
    for (int mi = 0; mi < 4; ++mi)
        #pragma unroll
        for (int ni = 0; ni < 4; ++ni)
            #pragma unroll
            for (int r = 0; r < 4; ++r) acc[mi][ni][r] = 0.f;

    const char* Ab = (const char*)(qb + (size_t)mbase * 512);
    const char* Bb = (const char*)(wkb + (size_t)nbase * 512);

    for (int kk = 0; kk < 512; kk += 32) {
        stage_tile(Ab + kk * 2, 1024, lA, tid);
        stage_tile(Bb + kk * 2, 1024, lB, tid);
        __syncthreads();
        const bf16x8* pA = (const bf16x8*)lA;
        const bf16x8* pB = (const bf16x8*)lB;
        bf16x8 af[4], bfr[4];
        #pragma unroll
        for (int mi = 0; mi < 4; ++mi)
            af[mi] = pA[(wr * 64 + mi * 16 + (lane & 15)) * 4 + (lane >> 4)];
        #pragma unroll
        for (int ni = 0; ni < 4; ++ni)
            bfr[ni] = pB[(wc * 64 + ni * 16 + (lane & 15)) * 4 + (lane >> 4)];
        #pragma unroll
        for (int mi = 0; mi < 4; ++mi)
            #pragma unroll
            for (int ni = 0; ni < 4; ++ni)
                acc[mi][ni] = __builtin_amdgcn_mfma_f32_16x16x32_bf16(af[mi], bfr[ni], acc[mi][ni], 0, 0, 0);
        __syncthreads();
    }

    #pragma unroll
    for (int ni = 0; ni < 4; ++ni) {
        const int ncol = nbase + wc * 64 + ni * 16 + (lane & 15);
        const float bkv = bkp[ncol];
        #pragma unroll
        for (int mi = 0; mi < 4; ++mi) {
            const int mrow0 = mbase + wr * 64 + mi * 16 + ((lane >> 4) << 2);
            #pragma unroll
            for (int r = 0; r < 4; ++r)
                coef[(size_t)(mrow0 + r) * 1536 + ncol] = f2bf(acc[mi][ni][r] + bkv);
        }
    }
}

// stage 2: out[b][i][j] = sum_t sum_c coef[b*1024+i][t*512+c] * kbp[b][j+t][c] + bias + bias_b
__global__ __launch_bounds__(256) void gemm2(const ushort_t* __restrict__ coef,
                                             const ushort_t* __restrict__ kbp,
                                             const float* __restrict__ biasw,
                                             const float* __restrict__ bias_b,
                                             float* __restrict__ out) {
    __shared__ alignas(16) char lA[8192];
    __shared__ alignas(16) char lB[8192];
    const int tid = threadIdx.x;
    const int lane = tid & 63, wid = tid >> 6;
    const int wr = wid >> 1, wc = wid & 1;
    const int jt = blockIdx.x, it = blockIdx.y, b = blockIdx.z;
    const int ibase = it * 128, jbase = jt * 128;

    f32x4 acc[4][4];
    #pragma unroll
    for (int mi = 0; mi < 4; ++mi)
        #pragma unroll
        for (int ni = 0; ni < 4; ++ni)
            #pragma unroll
            for (int r = 0; r < 4; ++r) acc[mi][ni][r] = 0.f;

    const char* Ab = (const char*)(coef + ((size_t)b * 1024 + ibase) * 1536);
    const char* Bb = (const char*)(kbp + (size_t)b * 1026 * 512);

    for (int t = 0; t < 3; ++t) {
        const char* At = Ab + t * 1024;                       // t*512 bf16
        const char* Bt = Bb + (size_t)(jbase + t) * 1024;     // shifted, pad-safe
        for (int kk = 0; kk < 512; kk += 32) {
            stage_tile(At + kk * 2, 3072, lA, tid);
            stage_tile(Bt + kk * 2, 1024, lB, tid);
            __syncthreads();
            const bf16x8* pA = (const bf16x8*)lA;
            const bf16x8* pB = (const bf16x8*)lB;
            bf16x8 af[4], bfr[4];
            #pragma unroll
            for (int mi = 0; mi < 4; ++mi)
                af[mi] = pA[(wr * 64 + mi * 16 + (lane & 15)) * 4 + (lane >> 4)];
            #pragma unroll
            for (int ni = 0; ni < 4; ++ni)
                bfr[ni] = pB[(wc * 64 + ni * 16 + (lane & 15)) * 4 + (lane >> 4)];
            #pragma unroll
            for (int mi = 0; mi < 4; ++mi)
                #pragma unroll
                for (int ni = 0; ni < 4; ++ni)
                    acc[mi][ni] = __builtin_amdgcn_mfma_f32_16x16x32_bf16(af[mi], bfr[ni], acc[mi][ni], 0, 0, 0);
            __syncthreads();
        }
    }

    const float bb0 = bias_b[0];
    #pragma unroll
    for (int mi = 0; mi < 4; ++mi) {
        const int irow0 = ibase + wr * 64 + mi * 16 + ((lane >> 4) << 2);
        #pragma unroll
        for (int r = 0; r < 4; ++r) {
            const float bv = biasw[b * 1024 + irow0 + r] + bb0;
            #pragma unroll
            for (int ni = 0; ni < 4; ++ni) {
                const int jcol = jbase + wc * 64 + ni * 16 + (lane & 15);
                out[((size_t)b << 20) + (size_t)(irow0 + r) * 1024 + jcol] = acc[mi][ni][r] + bv;
            }
        }
    }
}

extern "C" void kernel_launch(void* const* d_in, const int* in_sizes, int n_in,
                              void* d_out, int out_size, void* d_ws, size_t ws_size,
                              hipStream_t stream) {
    const float* q      = (const float*)d_in[0];
    const float* k      = (const float*)d_in[1];
    const float* Wk     = (const float*)d_in[2];
    const float* bk     = (const float*)d_in[3];
    const float* Wb     = (const float*)d_in[4];
    const float* bb     = (const float*)d_in[5];
    const float* bias_b = (const float*)d_in[6];
    float* out = (float*)d_out;

    // workspace layout (bf16 elements first, then fp32): ~85.6 MB total
    ushort_t* ws   = (ushort_t*)d_ws;
    ushort_t* qb   = ws;                                  // 16384*512
    ushort_t* kbp  = qb  + (size_t)16384 * 512;           // 16*1026*512 (zero-padded)
    ushort_t* wkb  = kbp + (size_t)16 * 1026 * 512;       // 1536*512 (rows permuted)
    ushort_t* coef = wkb + (size_t)1536 * 512;            // 16384*1536
    float*    biasw = (float*)(coef + (size_t)16384 * 1536);  // 16384
    float*    bkp   = biasw + 16384;                          // 1536

    prep_q<<<4096, 256, 0, stream>>>(q, Wb, bb, qb, biasw);
    prep_k<<<8976, 256, 0, stream>>>(k, Wk, bk, kbp, wkb, bkp);
    gemm1<<<dim3(128, 12), 256, 0, stream>>>(qb, wkb, bkp, coef);
    gemm2<<<dim3(8, 8, 16), 256, 0, stream>>>(coef, kbp, biasw, bias_b, out);
}

// Round 2
// 227.623 us; speedup vs baseline: 1.0927x; 1.0927x over previous
//
#include <hip/hip_runtime.h>

typedef unsigned short ushort_t;
typedef unsigned int uint32;
typedef __bf16 bf16x8 __attribute__((ext_vector_type(8)));
typedef float f32x4 __attribute__((ext_vector_type(4)));
typedef float f4 __attribute__((ext_vector_type(4)));
typedef unsigned short us4 __attribute__((ext_vector_type(4)));

// ---- constants for this problem shape ----
// B=16, QL=1024, KL=1024, QS=512, KS=512, KW=3, PAD=1
// gemm1: M=16384, N=1536, K=512   gemm2 (per b): M=1024, N=1024, K=1536 (3 shifted 512-segs)

__device__ __forceinline__ ushort_t f2bf(float f) {
    uint32 u = __builtin_bit_cast(uint32, f);
    u = (u + 0x7fffu + ((u >> 16) & 1u)) >> 16;  // RNE
    return (ushort_t)u;
}

#define FULL_BAR() do { __builtin_amdgcn_sched_barrier(0); __builtin_amdgcn_s_barrier(); __builtin_amdgcn_sched_barrier(0); } while (0)
#define HALF_BAR() do { __builtin_amdgcn_sched_barrier(0); __builtin_amdgcn_s_barrier(); } while (0)

// ---------------- prep: q -> bf16, and bias[m] = dot(q[m], Wb) + bb ----------------
__global__ __launch_bounds__(256) void prep_q(const float* __restrict__ q,
                                              const float* __restrict__ Wb,
                                              const float* __restrict__ bb,
                                              ushort_t* __restrict__ qb,
                                              float* __restrict__ biasw) {
    const int tid = threadIdx.x;
    const int lane = tid & 63, wid = tid >> 6;
    const int m = blockIdx.x * 4 + wid;
    const float* qrow = q + (size_t)m * 512;

    f4 v0 = *(const f4*)(qrow + lane * 4);
    f4 v1 = *(const f4*)(qrow + 256 + lane * 4);
    f4 w0 = *(const f4*)(Wb + lane * 4);
    f4 w1 = *(const f4*)(Wb + 256 + lane * 4);

    float dot = v0[0]*w0[0] + v0[1]*w0[1] + v0[2]*w0[2] + v0[3]*w0[3]
              + v1[0]*w1[0] + v1[1]*w1[1] + v1[2]*w1[2] + v1[3]*w1[3];

    us4 o0, o1;
    o0[0]=f2bf(v0[0]); o0[1]=f2bf(v0[1]); o0[2]=f2bf(v0[2]); o0[3]=f2bf(v0[3]);
    o1[0]=f2bf(v1[0]); o1[1]=f2bf(v1[1]); o1[2]=f2bf(v1[2]); o1[3]=f2bf(v1[3]);
    *(us4*)(qb + (size_t)m * 512 + lane * 4) = o0;
    *(us4*)(qb + (size_t)m * 512 + 256 + lane * 4) = o1;

    #pragma unroll
    for (int off = 32; off >= 1; off >>= 1) dot += __shfl_xor(dot, off);
    if (lane == 0) biasw[m] = dot + bb[0];
}

// ------- prep: k -> bf16 zero-padded [b][1026][512]; Wk row-permuted -> bf16; bk perm -------
__global__ __launch_bounds__(256) void prep_k(const float* __restrict__ k,
                                              const float* __restrict__ Wk,
                                              const float* __restrict__ bk,
                                              ushort_t* __restrict__ kbp,
                                              ushort_t* __restrict__ wkb,
                                              float* __restrict__ bkp) {
    const int gid = blockIdx.x * 256 + threadIdx.x;
    if (gid < 1536) bkp[gid] = bk[(gid & 511) * 3 + (gid >> 9)];

    const int KG = (16 * 1024 * 512) / 4;
    const int PG = (16 * 2 * 512) / 4;

    if (gid < KG) {
        const int e = gid * 4;
        const int b = e >> 19;
        const int rem = e & ((1 << 19) - 1);
        const int row = rem >> 9, c = rem & 511;
        f4 v = *(const f4*)(k + e);
        us4 o; o[0]=f2bf(v[0]); o[1]=f2bf(v[1]); o[2]=f2bf(v[2]); o[3]=f2bf(v[3]);
        *(us4*)(kbp + ((size_t)b * 1026 + row + 1) * 512 + c) = o;
    } else if (gid < KG + PG) {
        const int p = gid - KG;
        const int b = p >> 8, off = p & 255;
        const int row = (off < 128) ? 0 : 1025;
        const int c = (off & 127) * 4;
        us4 z; z[0]=0; z[1]=0; z[2]=0; z[3]=0;
        *(us4*)(kbp + ((size_t)b * 1026 + row) * 512 + c) = z;
    } else {
        const int w = gid - KG - PG;
        const int n = w >> 7;
        const int c = (w & 127) * 4;
        const int o = (n & 511) * 3 + (n >> 9);
        f4 v = *(const f4*)(Wk + (size_t)o * 512 + c);
        us4 ov; ov[0]=f2bf(v[0]); ov[1]=f2bf(v[1]); ov[2]=f2bf(v[2]); ov[3]=f2bf(v[3]);
        *(us4*)(wkb + (size_t)n * 512 + c) = ov;
    }
}

// ---- 256x256 tile, BK=32, 8 waves (2x4), double-buffered pipelined core ----
// LDS per buf: A 256x32 bf16 (16KB, swizzled) + B 256x32 (16KB) = 32KB; x2 = 64KB.
// Swizzle: 16B slot' = slot ^ ((row>>1)&3)  (applied on source addr; gload_lds dest linear)

__device__ __forceinline__ void stage16k(const char* base, int ld, char* dst, int tid) {
    #pragma unroll
    for (int inst = 0; inst < 2; ++inst) {
        const int idx = inst * 512 + tid;
        const int srow = idx >> 2;
        const int scol = ((idx & 3) ^ ((idx >> 3) & 3)) << 4;  // pre-swizzled source slot
        __builtin_amdgcn_global_load_lds(
            (const __attribute__((address_space(1))) void*)(base + (size_t)srow * (size_t)ld + scol),
            (__attribute__((address_space(3))) void*)(dst + (inst * 512 + (tid & ~63)) * 16),
            16, 0, 0);
    }
}

// gemm1: coef[m][n] = sum_k qb[m][k]*wkb[n][k] + bkp[n]  (bf16 out, n pre-permuted)
__global__ __launch_bounds__(512) void gemm1(const ushort_t* __restrict__ qb,
                                             const ushort_t* __restrict__ wkb,
                                             const float* __restrict__ bkp,
                                             ushort_t* __restrict__ coef) {
    __shared__ alignas(16) char lds[65536];
    const int tid = threadIdx.x;
    const int l = tid & 63, wid = tid >> 6;
    const int wr = wid >> 2, wc = wid & 3;       // 2 x 4 wave grid
    int bid = blockIdx.x;
    bid = (bid & 7) * 48 + (bid >> 3);           // XCD swizzle, 384 = 8*48
    const int mt = bid & 63, nt = bid >> 6;
    const int mbase = mt * 256, nbase = nt * 256;

    const char* Ag = (const char*)(qb + (size_t)mbase * 512);
    const char* Bg = (const char*)(wkb + (size_t)nbase * 512);
    const int NT = 16;

    const int r15 = l & 15, q = l >> 4;
    const int laneoff = r15 * 64 + (((q ^ (r15 >> 1)) & 3) << 4);
    const int wrA = wr * 8192 + laneoff;
    const int wcB = wc * 4096 + laneoff;

    f32x4 acc[8][4];
    #pragma unroll
    for (int mi = 0; mi < 8; ++mi)
        #pragma unroll
        for (int ni = 0; ni < 4; ++ni)
            #pragma unroll
            for (int r = 0; r < 4; ++r) acc[mi][ni][r] = 0.f;

    // prologue: t0.A, t0.B -> buf0; t1.A -> buf1
    stage16k(Ag, 1024, lds, tid);
    stage16k(Bg, 1024, lds + 16384, tid);
    stage16k(Ag + 64, 1024, lds + 32768, tid);
    asm volatile("s_waitcnt vmcnt(2)" ::: "memory");
    FULL_BAR();

    for (int t = 0; t < NT; ++t) {
        const int cur = (t & 1) << 15;
        const int nxt = cur ^ 32768;
        const char* lA = lds + cur;
        const char* lB = lds + cur + 16384;
        const int tn1 = (t + 1 < NT) ? t + 1 : NT - 1;
        const int tn2 = (t + 2 < NT) ? t + 2 : NT - 1;

        bf16x8 a[8], b0, b1;
        // ---- phase 1: n-frags 0,1 ----
        #pragma unroll
        for (int mi = 0; mi < 8; ++mi) a[mi] = *(const bf16x8*)(lA + wrA + mi * 1024);
        b0 = *(const bf16x8*)(lB + wcB);
        b1 = *(const bf16x8*)(lB + wcB + 1024);
        stage16k(Bg + tn1 * 64, 1024, lds + nxt + 16384, tid);   // t+1.B
        FULL_BAR();
        __builtin_amdgcn_s_setprio(1);
        #pragma unroll
        for (int mi = 0; mi < 8; ++mi) {
            acc[mi][0] = __builtin_amdgcn_mfma_f32_16x16x32_bf16(a[mi], b0, acc[mi][0], 0, 0, 0);
            acc[mi][1] = __builtin_amdgcn_mfma_f32_16x16x32_bf16(a[mi], b1, acc[mi][1], 0, 0, 0);
        }
        __builtin_amdgcn_s_setprio(0);
        HALF_BAR();
        // ---- phase 2: n-frags 2,3 ----
        b0 = *(const bf16x8*)(lB + wcB + 2048);
        b1 = *(const bf16x8*)(lB + wcB + 3072);
        stage16k(Ag + tn2 * 64, 1024, lds + cur, tid);           // t+2.A
        asm volatile("s_waitcnt vmcnt(2)" ::: "memory");
        FULL_BAR();
        __builtin_amdgcn_s_setprio(1);
        #pragma unroll
        for (int mi = 0; mi < 8; ++mi) {
            acc[mi][2] = __builtin_amdgcn_mfma_f32_16x16x32_bf16(a[mi], b0, acc[mi][2], 0, 0, 0);
            acc[mi][3] = __builtin_amdgcn_mfma_f32_16x16x32_bf16(a[mi], b1, acc[mi][3], 0, 0, 0);
        }
        __builtin_amdgcn_s_setprio(0);
        HALF_BAR();
    }

    #pragma unroll
    for (int ni = 0; ni < 4; ++ni) {
        const int ncol = nbase + wc * 64 + ni * 16 + r15;
        const float bkv = bkp[ncol];
        #pragma unroll
        for (int mi = 0; mi < 8; ++mi) {
            const int mrow0 = mbase + wr * 128 + mi * 16 + q * 4;
            #pragma unroll
            for (int r = 0; r < 4; ++r)
                coef[(size_t)(mrow0 + r) * 1536 + ncol] = f2bf(acc[mi][ni][r] + bkv);
        }
    }
}

// gemm2: out[b][i][j] = sum_t sum_c coef[b*1024+i][t*512+c]*kbp[b][j+t][c] + bias + bias_b
__global__ __launch_bounds__(512) void gemm2(const ushort_t* __restrict__ coef,
                                             const ushort_t* __restrict__ kbp,
                                             const float* __restrict__ biasw,
                                             const float* __restrict__ bias_b,
                                             float* __restrict__ out) {
    __shared__ alignas(16) char lds[65536];
    const int tid = threadIdx.x;
    const int l = tid & 63, wid = tid >> 6;
    const int wr = wid >> 2, wc = wid & 3;
    int bid = blockIdx.x;
    bid = (bid & 7) * 32 + (bid >> 3);           // XCD swizzle, 256 = 8*32
    const int jt = bid & 3, it = (bid >> 2) & 3, b = bid >> 4;
    const int ibase = it * 256, jbase = jt * 256;

    const char* Ag = (const char*)(coef + ((size_t)b * 1024 + ibase) * 1536);
    const char* Bg = (const char*)(kbp + ((size_t)b * 1026 + jbase) * 512);
    const int NT = 48;   // 3 segments x 16 tiles; tile tau: B row shift tau>>4, col (tau&15)*32

    const int r15 = l & 15, q = l >> 4;
    const int laneoff = r15 * 64 + (((q ^ (r15 >> 1)) & 3) << 4);
    const int wrA = wr * 8192 + laneoff;
    const int wcB = wc * 4096 + laneoff;

    f32x4 acc[8][4];
    #pragma unroll
    for (int mi = 0; mi < 8; ++mi)
        #pragma unroll
        for (int ni = 0; ni < 4; ++ni)
            #pragma unroll
            for (int r = 0; r < 4; ++r) acc[mi][ni][r] = 0.f;

    // prologue
    stage16k(Ag, 3072, lds, tid);
    stage16k(Bg, 1024, lds + 16384, tid);
    stage16k(Ag + 64, 3072, lds + 32768, tid);
    asm volatile("s_waitcnt vmcnt(2)" ::: "memory");
    FULL_BAR();

    for (int t = 0; t < NT; ++t) {
        const int cur = (t & 1) << 15;
        const int nxt = cur ^ 32768;
        const char* lA = lds + cur;
        const char* lB = lds + cur + 16384;
        const int tn1 = (t + 1 < NT) ? t + 1 : NT - 1;
        const int tn2 = (t + 2 < NT) ? t + 2 : NT - 1;

        bf16x8 a[8], b0, b1;
        // ---- phase 1 ----
        #pragma unroll
        for (int mi = 0; mi < 8; ++mi) a[mi] = *(const bf16x8*)(lA + wrA + mi * 1024);
        b0 = *(const bf16x8*)(lB + wcB);
        b1 = *(const bf16x8*)(lB + wcB + 1024);
        stage16k(Bg + (tn1 >> 4) * 1024 + (tn1 & 15) * 64, 1024, lds + nxt + 16384, tid);
        FULL_BAR();
        __builtin_amdgcn_s_setprio(1);
        #pragma unroll
        for (int mi = 0; mi < 8; ++mi) {
            acc[mi][0] = __builtin_amdgcn_mfma_f32_16x16x32_bf16(a[mi], b0, acc[mi][0], 0, 0, 0);
            acc[mi][1] = __builtin_amdgcn_mfma_f32_16x16x32_bf16(a[mi], b1, acc[mi][1], 0, 0, 0);
        }
        __builtin_amdgcn_s_setprio(0);
        HALF_BAR();
        // ---- phase 2 ----
        b0 = *(const bf16x8*)(lB + wcB + 2048);
        b1 = *(const bf16x8*)(lB + wcB + 3072);
        stage16k(Ag + tn2 * 64, 3072, lds + cur, tid);
        asm volatile("s_waitcnt vmcnt(2)" ::: "memory");
        FULL_BAR();
        __builtin_amdgcn_s_setprio(1);
        #pragma unroll
        for (int mi = 0; mi < 8; ++mi) {
            acc[mi][2] = __builtin_amdgcn_mfma_f32_16x16x32_bf16(a[mi], b0, acc[mi][2], 0, 0, 0);
            acc[mi][3] = __builtin_amdgcn_mfma_f32_16x16x32_bf16(a[mi], b1, acc[mi][3], 0, 0, 0);
        }
        __builtin_amdgcn_s_setprio(0);
        HALF_BAR();
    }

    const float bb0v = bias_b[0];
    #pragma unroll
    for (int mi = 0; mi < 8; ++mi) {
        const int irow0 = ibase + wr * 128 + mi * 16 + q * 4;
        #pragma unroll
        for (int r = 0; r < 4; ++r) {
            const float bv = biasw[b * 1024 + irow0 + r] + bb0v;
            #pragma unroll
            for (int ni = 0; ni < 4; ++ni) {
                const int jcol = jbase + wc * 64 + ni * 16 + r15;
                out[((size_t)b << 20) + (size_t)(irow0 + r) * 1024 + jcol] = acc[mi][ni][r] + bv;
            }
        }
    }
}

extern "C" void kernel_launch(void* const* d_in, const int* in_sizes, int n_in,
                              void* d_out, int out_size, void* d_ws, size_t ws_size,
                              hipStream_t stream) {
    const float* q      = (const float*)d_in[0];
    const float* k      = (const float*)d_in[1];
    const float* Wk     = (const float*)d_in[2];
    const float* bk     = (const float*)d_in[3];
    const float* Wb     = (const float*)d_in[4];
    const float* bb     = (const float*)d_in[5];
    const float* bias_b = (const float*)d_in[6];
    float* out = (float*)d_out;

    ushort_t* ws   = (ushort_t*)d_ws;
    ushort_t* qb   = ws;
    ushort_t* kbp  = qb  + (size_t)16384 * 512;
    ushort_t* wkb  = kbp + (size_t)16 * 1026 * 512;
    ushort_t* coef = wkb + (size_t)1536 * 512;
    float*    biasw = (float*)(coef + (size_t)16384 * 1536);
    float*    bkp   = biasw + 16384;

    prep_q<<<4096, 256, 0, stream>>>(q, Wb, bb, qb, biasw);
    prep_k<<<8976, 256, 0, stream>>>(k, Wk, bk, kbp, wkb, bkp);
    gemm1<<<384, 512, 0, stream>>>(qb, wkb, bkp, coef);
    gemm2<<<256, 512, 0, stream>>>(coef, kbp, biasw, bias_b, out);
}

// Round 3
// 226.692 us; speedup vs baseline: 1.0971x; 1.0041x over previous
//
#include <hip/hip_runtime.h>

typedef unsigned short ushort_t;
typedef unsigned int uint32;
typedef __bf16 bf16x8 __attribute__((ext_vector_type(8)));
typedef float f32x4 __attribute__((ext_vector_type(4)));
typedef float f4 __attribute__((ext_vector_type(4)));
typedef unsigned short us4 __attribute__((ext_vector_type(4)));

// ---- constants for this problem shape ----
// B=16, QL=1024, KL=1024, QS=512, KS=512, KW=3, PAD=1
// gemm1: M=16384, N=1536, K=512   gemm2 (per b): M=1024, N=1024, K=1536 (3 shifted 512-segs)

__device__ __forceinline__ ushort_t f2bf(float f) {
    uint32 u = __builtin_bit_cast(uint32, f);
    u = (u + 0x7fffu + ((u >> 16) & 1u)) >> 16;  // RNE
    return (ushort_t)u;
}

#define FULL_BAR() do { __builtin_amdgcn_sched_barrier(0); __builtin_amdgcn_s_barrier(); __builtin_amdgcn_sched_barrier(0); } while (0)
#define HALF_BAR() do { __builtin_amdgcn_sched_barrier(0); __builtin_amdgcn_s_barrier(); } while (0)

// ---------------- fused prep ----------------
// blocks 0..4095: q -> bf16 + biasw ;  blocks 4096..13071: k pad/cvt + Wk permute + bk perm
__global__ __launch_bounds__(256) void prep_all(const float* __restrict__ q,
                                                const float* __restrict__ Wb,
                                                const float* __restrict__ bb,
                                                const float* __restrict__ k,
                                                const float* __restrict__ Wk,
                                                const float* __restrict__ bk,
                                                ushort_t* __restrict__ qb,
                                                float* __restrict__ biasw,
                                                ushort_t* __restrict__ kbp,
                                                ushort_t* __restrict__ wkb,
                                                float* __restrict__ bkp) {
    const int tid = threadIdx.x;
    if (blockIdx.x < 4096) {
        const int lane = tid & 63, wid = tid >> 6;
        const int m = blockIdx.x * 4 + wid;
        const float* qrow = q + (size_t)m * 512;

        f4 v0 = *(const f4*)(qrow + lane * 4);
        f4 v1 = *(const f4*)(qrow + 256 + lane * 4);
        f4 w0 = *(const f4*)(Wb + lane * 4);
        f4 w1 = *(const f4*)(Wb + 256 + lane * 4);

        float dot = v0[0]*w0[0] + v0[1]*w0[1] + v0[2]*w0[2] + v0[3]*w0[3]
                  + v1[0]*w1[0] + v1[1]*w1[1] + v1[2]*w1[2] + v1[3]*w1[3];

        us4 o0, o1;
        o0[0]=f2bf(v0[0]); o0[1]=f2bf(v0[1]); o0[2]=f2bf(v0[2]); o0[3]=f2bf(v0[3]);
        o1[0]=f2bf(v1[0]); o1[1]=f2bf(v1[1]); o1[2]=f2bf(v1[2]); o1[3]=f2bf(v1[3]);
        *(us4*)(qb + (size_t)m * 512 + lane * 4) = o0;
        *(us4*)(qb + (size_t)m * 512 + 256 + lane * 4) = o1;

        #pragma unroll
        for (int off = 32; off >= 1; off >>= 1) dot += __shfl_xor(dot, off);
        if (lane == 0) biasw[m] = dot + bb[0];
        return;
    }
    const int gid = (blockIdx.x - 4096) * 256 + tid;
    if (gid < 1536) bkp[gid] = bk[(gid & 511) * 3 + (gid >> 9)];

    const int KG = (16 * 1024 * 512) / 4;
    const int PG = (16 * 2 * 512) / 4;

    if (gid < KG) {
        const int e = gid * 4;
        const int b = e >> 19;
        const int rem = e & ((1 << 19) - 1);
        const int row = rem >> 9, c = rem & 511;
        f4 v = *(const f4*)(k + e);
        us4 o; o[0]=f2bf(v[0]); o[1]=f2bf(v[1]); o[2]=f2bf(v[2]); o[3]=f2bf(v[3]);
        *(us4*)(kbp + ((size_t)b * 1026 + row + 1) * 512 + c) = o;
    } else if (gid < KG + PG) {
        const int p = gid - KG;
        const int b = p >> 8, off = p & 255;
        const int row = (off < 128) ? 0 : 1025;
        const int c = (off & 127) * 4;
        us4 z; z[0]=0; z[1]=0; z[2]=0; z[3]=0;
        *(us4*)(kbp + ((size_t)b * 1026 + row) * 512 + c) = z;
    } else {
        const int w = gid - KG - PG;
        const int n = w >> 7;
        const int c = (w & 127) * 4;
        const int o = (n & 511) * 3 + (n >> 9);
        f4 v = *(const f4*)(Wk + (size_t)o * 512 + c);
        us4 ov; ov[0]=f2bf(v[0]); ov[1]=f2bf(v[1]); ov[2]=f2bf(v[2]); ov[3]=f2bf(v[3]);
        *(us4*)(wkb + (size_t)n * 512 + c) = ov;
    }
}

// ---- 256x256 tile, BK=32, 8 waves (2x4), 4-deep buffered pipeline ----
// LDS: 4 buffers x (A 16KB + B 16KB) = 128KB. Swizzle: 16B slot' = slot ^ ((row>>1)&3),
// applied on the global source addr (gload_lds dest stays linear) and on ds_read addr.

__device__ __forceinline__ void stage16k(const char* base, int ld, char* dst, int tid) {
    #pragma unroll
    for (int inst = 0; inst < 2; ++inst) {
        const int idx = inst * 512 + tid;
        const int srow = idx >> 2;
        const int scol = ((idx & 3) ^ ((idx >> 3) & 3)) << 4;  // pre-swizzled source slot
        __builtin_amdgcn_global_load_lds(
            (const __attribute__((address_space(1))) void*)(base + (size_t)srow * (size_t)ld + scol),
            (__attribute__((address_space(3))) void*)(dst + (inst * 512 + (tid & ~63)) * 16),
            16, 0, 0);
    }
}

// Pipelined 256x256 GEMM core. Per K-tile: phase1 {read a[0..3],b[0..3]; stage A(t+3);
// bar; 16 MFMA mi0-3}; phase2 {read a[4..7]; stage B(t+3); vmcnt(8); bar; 16 MFMA mi4-7}.
#define GEMM_CORE(NT, A_OFF, B_OFF, A_LD, B_LD)                                            \
    stage16k(Ag + (size_t)(A_OFF(0)), A_LD, lds, tid);                                     \
    stage16k(Bg + (size_t)(B_OFF(0)), B_LD, lds + 16384, tid);                             \
    stage16k(Ag + (size_t)(A_OFF(1)), A_LD, lds + 32768, tid);                             \
    stage16k(Bg + (size_t)(B_OFF(1)), B_LD, lds + 32768 + 16384, tid);                     \
    stage16k(Ag + (size_t)(A_OFF(2)), A_LD, lds + 65536, tid);                             \
    stage16k(Bg + (size_t)(B_OFF(2)), B_LD, lds + 65536 + 16384, tid);                     \
    asm volatile("s_waitcnt vmcnt(8)" ::: "memory");                                       \
    FULL_BAR();                                                                            \
    for (int t = 0; t < NT; ++t) {                                                         \
        const char* lA = lds + ((t & 3) << 15);                                            \
        const char* lB = lA + 16384;                                                       \
        char* nb = lds + (((t + 3) & 3) << 15);                                            \
        const int tn3 = (t + 3 < NT) ? t + 3 : NT - 1;                                     \
        bf16x8 a[4], a2[4], b[4];                                                          \
        _Pragma("unroll")                                                                  \
        for (int mi = 0; mi < 4; ++mi) a[mi] = *(const bf16x8*)(lA + wrA + mi * 1024);     \
        _Pragma("unroll")                                                                  \
        for (int ni = 0; ni < 4; ++ni) b[ni] = *(const bf16x8*)(lB + wcB + ni * 1024);     \
        stage16k(Ag + (size_t)(A_OFF(tn3)), A_LD, nb, tid);                                \
        FULL_BAR();                                                                        \
        __builtin_amdgcn_s_setprio(1);                                                     \
        _Pragma("unroll")                                                                  \
        for (int mi = 0; mi < 4; ++mi)                                                     \
            _Pragma("unroll")                                                              \
            for (int ni = 0; ni < 4; ++ni)                                                 \
                acc[mi][ni] = __builtin_amdgcn_mfma_f32_16x16x32_bf16(a[mi], b[ni], acc[mi][ni], 0, 0, 0); \
        __builtin_amdgcn_s_setprio(0);                                                     \
        HALF_BAR();                                                                        \
        _Pragma("unroll")                                                                  \
        for (int mi = 0; mi < 4; ++mi) a2[mi] = *(const bf16x8*)(lA + wrA + (4 + mi) * 1024); \
        stage16k(Bg + (size_t)(B_OFF(tn3)), B_LD, nb + 16384, tid);                        \
        asm volatile("s_waitcnt vmcnt(8)" ::: "memory");                                   \
        FULL_BAR();                                                                        \
        __builtin_amdgcn_s_setprio(1);                                                     \
        _Pragma("unroll")                                                                  \
        for (int mi = 0; mi < 4; ++mi)                                                     \
            _Pragma("unroll")                                                              \
            for (int ni = 0; ni < 4; ++ni)                                                 \
                acc[4 + mi][ni] = __builtin_amdgcn_mfma_f32_16x16x32_bf16(a2[mi], b[ni], acc[4 + mi][ni], 0, 0, 0); \
        __builtin_amdgcn_s_setprio(0);                                                     \
        HALF_BAR();                                                                        \
    }

#define A1OFF(tt) ((tt) * 64)
#define B1OFF(tt) ((tt) * 64)
#define A2OFF(tt) ((tt) * 64)
#define B2OFF(tt) (((tt) >> 4) * 1024 + ((tt) & 15) * 64)

// gemm1: coef[m][n] = sum_k qb[m][k]*wkb[n][k] + bkp[n]  (bf16 out, n pre-permuted)
__global__ __launch_bounds__(512) void gemm1(const ushort_t* __restrict__ qb,
                                             const ushort_t* __restrict__ wkb,
                                             const float* __restrict__ bkp,
                                             ushort_t* __restrict__ coef) {
    __shared__ alignas(16) char lds[131072];
    const int tid = threadIdx.x;
    const int l = tid & 63, wid = tid >> 6;
    const int wr = wid >> 2, wc = wid & 3;       // 2 x 4 wave grid
    int bid = blockIdx.x;
    bid = (bid & 7) * 48 + (bid >> 3);           // XCD swizzle, 384 = 8*48
    const int mt = bid & 63, nt = bid >> 6;
    const int mbase = mt * 256, nbase = nt * 256;

    const char* Ag = (const char*)(qb + (size_t)mbase * 512);
    const char* Bg = (const char*)(wkb + (size_t)nbase * 512);

    const int r15 = l & 15, q = l >> 4;
    const int laneoff = r15 * 64 + (((q ^ (r15 >> 1)) & 3) << 4);
    const int wrA = wr * 8192 + laneoff;
    const int wcB = wc * 4096 + laneoff;

    f32x4 acc[8][4];
    #pragma unroll
    for (int mi = 0; mi < 8; ++mi)
        #pragma unroll
        for (int ni = 0; ni < 4; ++ni)
            #pragma unroll
            for (int r = 0; r < 4; ++r) acc[mi][ni][r] = 0.f;

    GEMM_CORE(16, A1OFF, B1OFF, 1024, 1024)

    #pragma unroll
    for (int ni = 0; ni < 4; ++ni) {
        const int ncol = nbase + wc * 64 + ni * 16 + r15;
        const float bkv = bkp[ncol];
        #pragma unroll
        for (int mi = 0; mi < 8; ++mi) {
            const int mrow0 = mbase + wr * 128 + mi * 16 + q * 4;
            #pragma unroll
            for (int r = 0; r < 4; ++r)
                coef[(size_t)(mrow0 + r) * 1536 + ncol] = f2bf(acc[mi][ni][r] + bkv);
        }
    }
}

// gemm2: out[b][i][j] = sum_t sum_c coef[b*1024+i][t*512+c]*kbp[b][j+t][c] + bias + bias_b
__global__ __launch_bounds__(512) void gemm2(const ushort_t* __restrict__ coef,
                                             const ushort_t* __restrict__ kbp,
                                             const float* __restrict__ biasw,
                                             const float* __restrict__ bias_b,
                                             float* __restrict__ out) {
    __shared__ alignas(16) char lds[131072];
    const int tid = threadIdx.x;
    const int l = tid & 63, wid = tid >> 6;
    const int wr = wid >> 2, wc = wid & 3;
    int bid = blockIdx.x;
    bid = (bid & 7) * 32 + (bid >> 3);           // XCD swizzle, 256 = 8*32
    const int jt = bid & 3, it = (bid >> 2) & 3, b = bid >> 4;
    const int ibase = it * 256, jbase = jt * 256;

    const char* Ag = (const char*)(coef + ((size_t)b * 1024 + ibase) * 1536);
    const char* Bg = (const char*)(kbp + ((size_t)b * 1026 + jbase) * 512);

    const int r15 = l & 15, q = l >> 4;
    const int laneoff = r15 * 64 + (((q ^ (r15 >> 1)) & 3) << 4);
    const int wrA = wr * 8192 + laneoff;
    const int wcB = wc * 4096 + laneoff;

    f32x4 acc[8][4];
    #pragma unroll
    for (int mi = 0; mi < 8; ++mi)
        #pragma unroll
        for (int ni = 0; ni < 4; ++ni)
            #pragma unroll
            for (int r = 0; r < 4; ++r) acc[mi][ni][r] = 0.f;

    GEMM_CORE(48, A2OFF, B2OFF, 3072, 1024)

    const float bb0v = bias_b[0];
    #pragma unroll
    for (int mi = 0; mi < 8; ++mi) {
        const int irow0 = ibase + wr * 128 + mi * 16 + q * 4;
        #pragma unroll
        for (int r = 0; r < 4; ++r) {
            const float bv = biasw[b * 1024 + irow0 + r] + bb0v;
            #pragma unroll
            for (int ni = 0; ni < 4; ++ni) {
                const int jcol = jbase + wc * 64 + ni * 16 + r15;
                out[((size_t)b << 20) + (size_t)(irow0 + r) * 1024 + jcol] = acc[mi][ni][r] + bv;
            }
        }
    }
}

extern "C" void kernel_launch(void* const* d_in, const int* in_sizes, int n_in,
                              void* d_out, int out_size, void* d_ws, size_t ws_size,
                              hipStream_t stream) {
    const float* q      = (const float*)d_in[0];
    const float* k      = (const float*)d_in[1];
    const float* Wk     = (const float*)d_in[2];
    const float* bk     = (const float*)d_in[3];
    const float* Wb     = (const float*)d_in[4];
    const float* bb     = (const float*)d_in[5];
    const float* bias_b = (const float*)d_in[6];
    float* out = (float*)d_out;

    ushort_t* ws   = (ushort_t*)d_ws;
    ushort_t* qb   = ws;
    ushort_t* kbp  = qb  + (size_t)16384 * 512;
    ushort_t* wkb  = kbp + (size_t)16 * 1026 * 512;
    ushort_t* coef = wkb + (size_t)1536 * 512;
    float*    biasw = (float*)(coef + (size_t)16384 * 1536);
    float*    bkp   = biasw + 16384;

    prep_all<<<13072, 256, 0, stream>>>(q, Wb, bb, k, Wk, bk, qb, biasw, kbp, wkb, bkp);
    gemm1<<<384, 512, 0, stream>>>(qb, wkb, bkp, coef);
    gemm2<<<256, 512, 0, stream>>>(coef, kbp, biasw, bias_b, out);
}

// Round 5
// 216.733 us; speedup vs baseline: 1.1476x; 1.0460x over previous
//
#include <hip/hip_runtime.h>

typedef unsigned short ushort_t;
typedef unsigned int uint32;
typedef __bf16 bf16x8 __attribute__((ext_vector_type(8)));
typedef float f32x4 __attribute__((ext_vector_type(4)));
typedef float f4 __attribute__((ext_vector_type(4)));
typedef unsigned short us4 __attribute__((ext_vector_type(4)));

// ---- constants for this problem shape ----
// B=16, QL=1024, KL=1024, QS=512, KS=512, KW=3, PAD=1
// gemm1: M=16384, N=1536, K=512   gemm2 (per b): M=1024, N=1024, K=1536 (3 shifted 512-segs)

__device__ __forceinline__ ushort_t f2bf(float f) {
    uint32 u = __builtin_bit_cast(uint32, f);
    u = (u + 0x7fffu + ((u >> 16) & 1u)) >> 16;  // RNE
    return (ushort_t)u;
}

#define FULL_BAR() do { __builtin_amdgcn_sched_barrier(0); __builtin_amdgcn_s_barrier(); __builtin_amdgcn_sched_barrier(0); } while (0)
#define HALF_BAR() do { __builtin_amdgcn_sched_barrier(0); __builtin_amdgcn_s_barrier(); } while (0)
// pre-MFMA fence: barrier, drain own ds_reads, pin order (rule #18)
#define PRE_MFMA() do { __builtin_amdgcn_sched_barrier(0); __builtin_amdgcn_s_barrier(); \
    asm volatile("s_waitcnt lgkmcnt(0)" ::: "memory"); __builtin_amdgcn_sched_barrier(0); } while (0)

#define AS1 __attribute__((address_space(1)))
#define AS3 __attribute__((address_space(3)))

// ---------------- fused prep ----------------
__global__ __launch_bounds__(256) void prep_all(const float* __restrict__ q,
                                                const float* __restrict__ Wb,
                                                const float* __restrict__ bb,
                                                const float* __restrict__ k,
                                                const float* __restrict__ Wk,
                                                const float* __restrict__ bk,
                                                ushort_t* __restrict__ qb,
                                                float* __restrict__ biasw,
                                                ushort_t* __restrict__ kbp,
                                                ushort_t* __restrict__ wkb,
                                                float* __restrict__ bkp) {
    const int tid = threadIdx.x;
    if (blockIdx.x < 4096) {
        const int lane = tid & 63, wid = tid >> 6;
        const int m = blockIdx.x * 4 + wid;
        const float* qrow = q + (size_t)m * 512;

        f4 v0 = *(const f4*)(qrow + lane * 4);
        f4 v1 = *(const f4*)(qrow + 256 + lane * 4);
        f4 w0 = *(const f4*)(Wb + lane * 4);
        f4 w1 = *(const f4*)(Wb + 256 + lane * 4);

        float dot = v0[0]*w0[0] + v0[1]*w0[1] + v0[2]*w0[2] + v0[3]*w0[3]
                  + v1[0]*w1[0] + v1[1]*w1[1] + v1[2]*w1[2] + v1[3]*w1[3];

        us4 o0, o1;
        o0[0]=f2bf(v0[0]); o0[1]=f2bf(v0[1]); o0[2]=f2bf(v0[2]); o0[3]=f2bf(v0[3]);
        o1[0]=f2bf(v1[0]); o1[1]=f2bf(v1[1]); o1[2]=f2bf(v1[2]); o1[3]=f2bf(v1[3]);
        *(us4*)(qb + (size_t)m * 512 + lane * 4) = o0;
        *(us4*)(qb + (size_t)m * 512 + 256 + lane * 4) = o1;

        #pragma unroll
        for (int off = 32; off >= 1; off >>= 1) dot += __shfl_xor(dot, off);
        if (lane == 0) biasw[m] = dot + bb[0];
        return;
    }
    const int gid = (blockIdx.x - 4096) * 256 + tid;
    if (gid < 1536) bkp[gid] = bk[(gid & 511) * 3 + (gid >> 9)];

    const int KG = (16 * 1024 * 512) / 4;
    const int PG = (16 * 2 * 512) / 4;

    if (gid < KG) {
        const int e = gid * 4;
        const int b = e >> 19;
        const int rem = e & ((1 << 19) - 1);
        const int row = rem >> 9, c = rem & 511;
        f4 v = *(const f4*)(k + e);
        us4 o; o[0]=f2bf(v[0]); o[1]=f2bf(v[1]); o[2]=f2bf(v[2]); o[3]=f2bf(v[3]);
        *(us4*)(kbp + ((size_t)b * 1026 + row + 1) * 512 + c) = o;
    } else if (gid < KG + PG) {
        const int p = gid - KG;
        const int b = p >> 8, off = p & 255;
        const int row = (off < 128) ? 0 : 1025;
        const int c = (off & 127) * 4;
        us4 z; z[0]=0; z[1]=0; z[2]=0; z[3]=0;
        *(us4*)(kbp + ((size_t)b * 1026 + row) * 512 + c) = z;
    } else {
        const int w = gid - KG - PG;
        const int n = w >> 7;
        const int c = (w & 127) * 4;
        const int o = (n & 511) * 3 + (n >> 9);
        f4 v = *(const f4*)(Wk + (size_t)o * 512 + c);
        us4 ov; ov[0]=f2bf(v[0]); ov[1]=f2bf(v[1]); ov[2]=f2bf(v[2]); ov[3]=f2bf(v[3]);
        *(us4*)(wkb + (size_t)n * 512 + c) = ov;
    }
}

// ---- staging: one K-half panel = rows x 64B, linear in LDS, col-swizzled on global src.
// LDS slot s of row holds global slot s ^ ((row>>1)&3); reader XORs the same (involution).
template<int NINST>
__device__ __forceinline__ void stage_half(const char* base, int ld, char* dst, int tid) {
    #pragma unroll
    for (int inst = 0; inst < NINST; ++inst) {
        const int idx = inst * 512 + tid;
        const int row = idx >> 2;
        const int scol = ((idx & 3) ^ ((row >> 1) & 3)) << 4;
        __builtin_amdgcn_global_load_lds(
            (const AS1 void*)(base + (size_t)row * (size_t)ld + scol),
            (AS3 void*)(dst + (size_t)(inst * 512 + (tid & ~63)) * 16),
            16, 0, 0);
    }
}

#define MFMA_CLUSTER(af, bf, accrow)                                         \
    __builtin_amdgcn_s_setprio(1);                                           \
    _Pragma("unroll")                                                        \
    for (int i_ = 0; i_ < 4; ++i_)                                           \
        _Pragma("unroll")                                                    \
        for (int j_ = 0; j_ < 4; ++j_)                                       \
            acc[(accrow) + i_][j_] = __builtin_amdgcn_mfma_f32_16x16x32_bf16( \
                af[i_], bf[j_], acc[(accrow) + i_][j_], 0, 0, 0);            \
    __builtin_amdgcn_s_setprio(0);

// gemm1: 128x256 tile, BK=64, 8 waves (2x4), per-wave 64x64. LDS 2x48KB dbuf.
// Per K-tile: 2 phases x 16 MFMA; stage 3 instr/phase; vmcnt(3) at each phase end
// (guarantees the panels needed one phase later). Prologue: full tile0 + vmcnt(3).
__global__ __launch_bounds__(512) void gemm1(const ushort_t* __restrict__ qb,
                                             const ushort_t* __restrict__ wkb,
                                             const float* __restrict__ bkp,
                                             ushort_t* __restrict__ coef) {
    __shared__ alignas(16) char lds[98304];
    const int tid = threadIdx.x;
    const int l = tid & 63, wid = tid >> 6;
    const int wr = wid >> 2, wc = wid & 3;       // 2 x 4 wave grid
    int bid = blockIdx.x;
    bid = (bid & 7) * 96 + (bid >> 3);           // XCD swizzle, 768 = 8*96
    const int mt = bid & 127, nt = bid >> 7;     // 128 m-tiles x 6 n-tiles
    const int mbase = mt * 128, nbase = nt * 256;

    const char* Ag = (const char*)(qb + (size_t)mbase * 512);
    const char* Bg = (const char*)(wkb + (size_t)nbase * 512);

    const int r15 = l & 15, q = l >> 4;
    const int swz = ((q ^ (r15 >> 1)) & 3) << 4;
    const int laneA = (wr * 64 + r15) * 64 + swz;
    const int laneB = (wc * 64 + r15) * 64 + swz;

    f32x4 acc[4][4];
    #pragma unroll
    for (int mi = 0; mi < 4; ++mi)
        #pragma unroll
        for (int ni = 0; ni < 4; ++ni)
            #pragma unroll
            for (int r = 0; r < 4; ++r) acc[mi][ni][r] = 0.f;

    // buffer layout (48KB): Ah0@0(8K) Ah1@8192(8K) Bh0@16384(16K) Bh1@32768(16K)
    // prologue: full tile 0, then wait for Ah0+Bh0 (oldest 3 of 6)
    stage_half<1>(Ag, 1024, lds, tid);
    stage_half<2>(Bg, 1024, lds + 16384, tid);
    stage_half<1>(Ag + 64, 1024, lds + 8192, tid);
    stage_half<2>(Bg + 64, 1024, lds + 32768, tid);
    asm volatile("s_waitcnt vmcnt(3)" ::: "memory");
    FULL_BAR();

    for (int t = 0; t < 8; ++t) {
        const char* bA = lds + ((t & 1) ? 49152 : 0);
        char* nb = lds + ((t & 1) ? 0 : 49152);
        const int tn = (t < 7) ? t + 1 : t;
        const size_t off = (size_t)tn * 128;

        // ---- P0: k-half 0 (reads 8); stage Ah0,Bh0(t+1); vmcnt(3) -> Ah1,Bh1(t) ready
        bf16x8 a0[4], b0[4];
        #pragma unroll
        for (int i = 0; i < 4; ++i) a0[i] = *(const bf16x8*)(bA + laneA + i * 1024);
        #pragma unroll
        for (int j = 0; j < 4; ++j) b0[j] = *(const bf16x8*)(bA + 16384 + laneB + j * 1024);
        stage_half<1>(Ag + off, 1024, nb, tid);
        stage_half<2>(Bg + off, 1024, nb + 16384, tid);
        asm volatile("s_waitcnt vmcnt(3)" ::: "memory");
        PRE_MFMA();
        MFMA_CLUSTER(a0, b0, 0)
        HALF_BAR();

        // ---- P1: k-half 1 (reads 8); stage Ah1,Bh1(t+1); vmcnt(3) -> Ah0,Bh0(t+1) ready
        bf16x8 a1[4], b1[4];
        #pragma unroll
        for (int i = 0; i < 4; ++i) a1[i] = *(const bf16x8*)(bA + 8192 + laneA + i * 1024);
        #pragma unroll
        for (int j = 0; j < 4; ++j) b1[j] = *(const bf16x8*)(bA + 32768 + laneB + j * 1024);
        stage_half<1>(Ag + off + 64, 1024, nb + 8192, tid);
        stage_half<2>(Bg + off + 64, 1024, nb + 32768, tid);
        asm volatile("s_waitcnt vmcnt(3)" ::: "memory");
        PRE_MFMA();
        MFMA_CLUSTER(a1, b1, 0)
        HALF_BAR();
    }

    #pragma unroll
    for (int ni = 0; ni < 4; ++ni) {
        const int ncol = nbase + wc * 64 + ni * 16 + r15;
        const float bkv = bkp[ncol];
        #pragma unroll
        for (int mi = 0; mi < 4; ++mi) {
            const int mrow0 = mbase + wr * 64 + mi * 16 + q * 4;
            #pragma unroll
            for (int r = 0; r < 4; ++r)
                coef[(size_t)(mrow0 + r) * 1536 + ncol] = f2bf(acc[mi][ni][r] + bkv);
        }
    }
}

// gemm2: 256x256 tile, BK=64, 8 waves (2x4), per-wave 128x64. LDS 2x64KB dbuf.
// Per K-tile: 4 phases x 16 MFMA (reads 8/4/8/4); stage order [Ah0,Bh0,Ah1,Bh1], one
// 2-instr stage per phase; vmcnt(4) at ends of P1 (Ah1/Bh1(t) ready) and P3
// (Ah0/Bh0(t+1) ready). Counted, never 0; loads ~3-4 phases in flight.
__global__ __launch_bounds__(512) void gemm2(const ushort_t* __restrict__ coef,
                                             const ushort_t* __restrict__ kbp,
                                             const float* __restrict__ biasw,
                                             const float* __restrict__ bias_b,
                                             float* __restrict__ out) {
    __shared__ alignas(16) char lds[131072];
    const int tid = threadIdx.x;
    const int l = tid & 63, wid = tid >> 6;
    const int wr = wid >> 2, wc = wid & 3;
    int bid = blockIdx.x;
    bid = (bid & 7) * 32 + (bid >> 3);           // XCD swizzle, 256 = 8*32
    const int jt = bid & 3, it = (bid >> 2) & 3, b = bid >> 4;
    const int ibase = it * 256, jbase = jt * 256;

    const char* Ag = (const char*)(coef + ((size_t)b * 1024 + ibase) * 1536);
    const char* Bg = (const char*)(kbp + ((size_t)b * 1026 + jbase) * 512);

    const int r15 = l & 15, q = l >> 4;
    const int swz = ((q ^ (r15 >> 1)) & 3) << 4;
    const int laneA = (wr * 128 + r15) * 64 + swz;
    const int laneB = (wc * 64 + r15) * 64 + swz;

    f32x4 acc[8][4];
    #pragma unroll
    for (int mi = 0; mi < 8; ++mi)
        #pragma unroll
        for (int ni = 0; ni < 4; ++ni)
            #pragma unroll
            for (int r = 0; r < 4; ++r) acc[mi][ni][r] = 0.f;

    // buffer layout (64KB): Ah0@0(16K) Ah1@16384 Bh0@32768 Bh1@49152
    // prologue: full tile 0 in read-need order, wait oldest 4 (Ah0,Bh0)
    stage_half<2>(Ag, 3072, lds, tid);
    stage_half<2>(Bg, 1024, lds + 32768, tid);
    stage_half<2>(Ag + 64, 3072, lds + 16384, tid);
    stage_half<2>(Bg + 64, 1024, lds + 49152, tid);
    asm volatile("s_waitcnt vmcnt(4)" ::: "memory");
    FULL_BAR();

    for (int t = 0; t < 24; ++t) {
        const char* bA = lds + ((t & 1) << 16);
        char* nb = lds + (((t + 1) & 1) << 16);
        const int tn = (t < 23) ? t + 1 : t;
        const size_t aoff = (size_t)tn * 128;
        const size_t boff = (size_t)(tn >> 3) * 1024 + (size_t)(tn & 7) * 128;

        // ---- P0: kk0, mi 0-3 (reads 8); stage Ah0(t+1)
        bf16x8 a0[4], b0[4];
        #pragma unroll
        for (int i = 0; i < 4; ++i) a0[i] = *(const bf16x8*)(bA + laneA + i * 1024);
        #pragma unroll
        for (int j = 0; j < 4; ++j) b0[j] = *(const bf16x8*)(bA + 32768 + laneB + j * 1024);
        stage_half<2>(Ag + aoff, 3072, nb, tid);
        PRE_MFMA();
        MFMA_CLUSTER(a0, b0, 0)
        HALF_BAR();

        // ---- P1: kk0, mi 4-7 (reads 4); stage Bh0(t+1); vmcnt(4) -> Ah1,Bh1(t) ready
        bf16x8 a1[4];
        #pragma unroll
        for (int i = 0; i < 4; ++i) a1[i] = *(const bf16x8*)(bA + laneA + (4 + i) * 1024);
        stage_half<2>(Bg + boff, 1024, nb + 32768, tid);
        asm volatile("s_waitcnt vmcnt(4)" ::: "memory");
        PRE_MFMA();
        MFMA_CLUSTER(a1, b0, 4)
        HALF_BAR();

        // ---- P2: kk1, mi 0-3 (reads 8); stage Ah1(t+1)
        bf16x8 a2[4], b1[4];
        #pragma unroll
        for (int i = 0; i < 4; ++i) a2[i] = *(const bf16x8*)(bA + 16384 + laneA + i * 1024);
        #pragma unroll
        for (int j = 0; j < 4; ++j) b1[j] = *(const bf16x8*)(bA + 49152 + laneB + j * 1024);
        stage_half<2>(Ag + aoff + 64, 3072, nb + 16384, tid);
        PRE_MFMA();
        MFMA_CLUSTER(a2, b1, 0)
        HALF_BAR();

        // ---- P3: kk1, mi 4-7 (reads 4); stage Bh1(t+1); vmcnt(4) -> Ah0,Bh0(t+1) ready
        bf16x8 a3[4];
        #pragma unroll
        for (int i = 0; i < 4; ++i) a3[i] = *(const bf16x8*)(bA + 16384 + laneA + (4 + i) * 1024);
        stage_half<2>(Bg + boff + 64, 1024, nb + 49152, tid);
        asm volatile("s_waitcnt vmcnt(4)" ::: "memory");
        PRE_MFMA();
        MFMA_CLUSTER(a3, b1, 4)
        HALF_BAR();
    }

    const float bb0v = bias_b[0];
    #pragma unroll
    for (int mi = 0; mi < 8; ++mi) {
        const int irow0 = ibase + wr * 128 + mi * 16 + q * 4;
        #pragma unroll
        for (int r = 0; r < 4; ++r) {
            const float bv = biasw[b * 1024 + irow0 + r] + bb0v;
            #pragma unroll
            for (int ni = 0; ni < 4; ++ni) {
                const int jcol = jbase + wc * 64 + ni * 16 + r15;
                out[((size_t)b << 20) + (size_t)(irow0 + r) * 1024 + jcol] = acc[mi][ni][r] + bv;
            }
        }
    }
}

extern "C" void kernel_launch(void* const* d_in, const int* in_sizes, int n_in,
                              void* d_out, int out_size, void* d_ws, size_t ws_size,
                              hipStream_t stream) {
    const float* q      = (const float*)d_in[0];
    const float* k      = (const float*)d_in[1];
    const float* Wk     = (const float*)d_in[2];
    const float* bk     = (const float*)d_in[3];
    const float* Wb     = (const float*)d_in[4];
    const float* bb     = (const float*)d_in[5];
    const float* bias_b = (const float*)d_in[6];
    float* out = (float*)d_out;

    ushort_t* ws   = (ushort_t*)d_ws;
    ushort_t* qb   = ws;
    ushort_t* kbp  = qb  + (size_t)16384 * 512;
    ushort_t* wkb  = kbp + (size_t)16 * 1026 * 512;
    ushort_t* coef = wkb + (size_t)1536 * 512;
    float*    biasw = (float*)(coef + (size_t)16384 * 1536);
    float*    bkp   = biasw + 16384;

    prep_all<<<13072, 256, 0, stream>>>(q, Wb, bb, k, Wk, bk, qb, biasw, kbp, wkb, bkp);
    gemm1<<<768, 512, 0, stream>>>(qb, wkb, bkp, coef);
    gemm2<<<256, 512, 0, stream>>>(coef, kbp, biasw, bias_b, out);
}